// Round 4
// baseline (859.235 us; speedup 1.0000x reference)
//
#include <hip/hip_runtime.h>

#define NN      100000
#define MHE     200000
#define EE      2000000
#define HID     64

typedef unsigned short u16;
typedef unsigned int   u32;

__device__ __forceinline__ float bf2f(u16 u) { return __uint_as_float(((u32)u) << 16); }
__device__ __forceinline__ u16 f2bf(float f) {
    u32 u = __float_as_uint(f);
    return (u16)((u + 0x7fffu + ((u >> 16) & 1u)) >> 16);
}
__device__ __forceinline__ float lo16(u32 v) { return __uint_as_float(v << 16); }
__device__ __forceinline__ float hi16(u32 v) { return __uint_as_float(v & 0xffff0000u); }

// dtype-aware scalar load/store (isf32: 1 = float32 buffers, 0 = bf16 buffers)
__device__ __forceinline__ float ldv(const void* p, long i, int isf32) {
    return isf32 ? ((const float*)p)[i] : bf2f(((const u16*)p)[i]);
}
__device__ __forceinline__ u16 ldb(const void* p, long i, int isf32) {
    return isf32 ? f2bf(((const float*)p)[i]) : ((const u16*)p)[i];
}
__device__ __forceinline__ void stv(void* p, long i, float v, int isf32) {
    if (isf32) ((float*)p)[i] = v;
    else       ((u16*)p)[i] = f2bf(v);
}

// ---- ws layout (floats) ----
#define OFF_EX    0           // ex16  [2][MHE][16]  (6,400,000)
#define OFF_AGG   6400000     // agg16 [2][NN][16]   (3,200,000)
#define OFF_BDEG  9600000     // [2][MHE]            (400,000)
#define OFF_DDEG  10000000    // [2][NN]             (200,000)
#define OFF_WC    10200000    // [2][16][64] f32     (2,048)
#define OFF_BCOMB 10202048    // [64]
#define OFF_WIH   10202112    // 6144 u32
#define OFF_WHH   10208256    // 6144 u32
#define OFF_FLAG  10214400    // 1 u32
#define ZERO_BYTES (10200000UL * 4UL)

// Detect input dtype: decode low u16 of first 1024 words of x as bf16.
// True bf16 N(0,1) data never has |v|>1e10; f32 mantissa-low garbage does ~37% of the time.
__global__ void detect_kernel(const u32* __restrict__ xw, u32* __restrict__ flag) {
    __shared__ int cnt;
    if (threadIdx.x == 0) cnt = 0;
    __syncthreads();
    int hits = 0;
    for (int i = threadIdx.x; i < 1024; i += 256) {
        float v = bf2f((u16)(xw[i] & 0xffffu));
        if (!(fabsf(v) < 1e10f)) hits++;   // catches NaN/Inf too
    }
    atomicAdd(&cnt, hits);
    __syncthreads();
    if (threadIdx.x == 0) flag[0] = (cnt >= 16) ? 1u : 0u;
}

// One-block setup: pack GRU weights (transposed bf16x2), build combined Wc and bcomb in f32.
__global__ __launch_bounds__(256) void setup_kernel(
        const void* __restrict__ W_conv, const void* __restrict__ b_conv,
        const void* __restrict__ W_mix,  const void* __restrict__ b_mix,
        const void* __restrict__ W_ih,   const void* __restrict__ W_hh,
        float* __restrict__ Wc, float* __restrict__ bcomb,
        u32* __restrict__ Wih_pk, u32* __restrict__ Whh_pk,
        const u32* __restrict__ flag) {
    int isf = (int)flag[0];
    int tid = threadIdx.x;
    for (int i = tid; i < 6144; i += 256) {
        int p = i / 192, j = i % 192;
        Wih_pk[i] = (u32)ldb(W_ih, j * 64 + 2 * p, isf) | ((u32)ldb(W_ih, j * 64 + 2 * p + 1, isf) << 16);
        Whh_pk[i] = (u32)ldb(W_hh, j * 64 + 2 * p, isf) | ((u32)ldb(W_hh, j * 64 + 2 * p + 1, isf) << 16);
    }
    // Wc[t][k][j] = sum_c W_conv[t][k][c] * W_mix[t*64+c][j]
    for (int i = tid; i < 2048; i += 256) {
        int t = i >> 10, rem = i & 1023, k = rem >> 6, j = rem & 63;
        float acc = 0.f;
        for (int c = 0; c < 64; c++)
            acc += ldv(W_conv, (t * 16 + k) * 64 + c, isf) * ldv(W_mix, (t * 64 + c) * 64 + j, isf);
        Wc[i] = acc;
    }
    // bcomb[j] = b_mix[j] + sum_c bcat[c] * W_mix[c][j]
    if (tid < 64) {
        float acc = ldv(b_mix, tid, isf);
        for (int c = 0; c < 128; c++)
            acc += ldv(b_conv, c, isf) * ldv(W_mix, c * 64 + tid, isf);
        bcomb[tid] = acc;
    }
}

__global__ void deg_kernel(const int* __restrict__ en, const int* __restrict__ eh,
                           const int* __restrict__ ea,
                           float* __restrict__ Bdeg, float* __restrict__ Ddeg) {
    int i = blockIdx.x * 256 + threadIdx.x;
    if (i >= EE) return;
    int t = ea[i];
    atomicAdd(Bdeg + t * MHE + eh[i], 1.0f);
    atomicAdd(Ddeg + t * NN + en[i], 1.0f);
}

// node -> hyperedge: accumulate raw 16-dim x sums per (type, hedge). 16 lanes per edge.
__global__ __launch_bounds__(256) void scat1(const int* __restrict__ en, const int* __restrict__ eh,
                                             const int* __restrict__ ea,
                                             const void* __restrict__ x,
                                             float* __restrict__ ex16,
                                             const u32* __restrict__ flag) {
    int isf = (int)flag[0];
    int sub = threadIdx.x & 15;
    int gid = (blockIdx.x * 256 + threadIdx.x) >> 4;
    int ng  = (gridDim.x * 256) >> 4;
    for (int e = gid; e < EE; e += ng) {
        int t = ea[e], node = en[e], he = eh[e];
        float v = ldv(x, (long)node * 16 + sub, isf);
        atomicAdd(ex16 + ((long)t * MHE + he) * 16 + sub, v);
    }
}

// hyperedge -> node: scatter Binv-scaled 16-dim sums per (type, node). 16 lanes per edge.
__global__ __launch_bounds__(256) void scat2(const int* __restrict__ en, const int* __restrict__ eh,
                                             const int* __restrict__ ea,
                                             const float* __restrict__ ex16,
                                             const float* __restrict__ Bdeg,
                                             float* __restrict__ agg16) {
    int sub = threadIdx.x & 15;
    int gid = (blockIdx.x * 256 + threadIdx.x) >> 4;
    int ng  = (gridDim.x * 256) >> 4;
    for (int e = gid; e < EE; e += ng) {
        int t = ea[e], node = en[e], he = eh[e];
        float bd = Bdeg[(long)t * MHE + he];                 // >=1 structurally
        float v  = ex16[((long)t * MHE + he) * 16 + sub] * (1.0f / fmaxf(bd, 1.0f));
        atomicAdd(agg16 + ((long)t * NN + node) * 16 + sub, v);
    }
}

// Fused: h = relu(sum_t Dinv_t*(agg16_t @ Wc_t) + bcomb); GRUCell; pred = (h_next@W_out+b_out)[:,:3]
__global__ __launch_bounds__(256) void epilogue(const float* __restrict__ agg16,
                                                const float* __restrict__ Ddeg,
                                                const float* __restrict__ Wc_g,
                                                const float* __restrict__ bcomb,
                                                const u32* __restrict__ Wih_pk,
                                                const u32* __restrict__ Whh_pk,
                                                const void* __restrict__ b_ih, const void* __restrict__ b_hh,
                                                const void* __restrict__ h_prev,
                                                const void* __restrict__ W_out, const void* __restrict__ b_out,
                                                void* __restrict__ out,
                                                const u32* __restrict__ flag) {
    __shared__ u32 Wi[6144], Wh[6144];      // 48 KB
    __shared__ float Wcs[2048];             // 8 KB
    __shared__ float bc[64];
    __shared__ float hv[4][32];
    __shared__ float hs[4][64], hps[4][64];
    int isf = (int)flag[0];
    int tid = threadIdx.x;
    for (int i = tid; i < 6144; i += 256) { Wi[i] = Wih_pk[i]; Wh[i] = Whh_pk[i]; }
    for (int i = tid; i < 2048; i += 256) Wcs[i] = Wc_g[i];
    if (tid < 64) bc[tid] = bcomb[tid];
    int w = tid >> 6, lane = tid & 63;
    for (int g = blockIdx.x; g < NN / 4; g += gridDim.x) {
        int n = g * 4 + w;
        __syncthreads();
        if (lane < 32) {
            int t = lane >> 4, k = lane & 15;
            hv[w][lane] = agg16[((long)t * NN + n) * 16 + k];
        }
        hps[w][lane] = ldv(h_prev, (long)n * 64 + lane, isf);
        __syncthreads();
        float d0 = Ddeg[n], d1 = Ddeg[NN + n];
        float i0 = d0 > 0.f ? 1.0f / d0 : 0.f;
        float i1 = d1 > 0.f ? 1.0f / d1 : 0.f;
        float a0 = 0.f, a1 = 0.f;
        #pragma unroll
        for (int k = 0; k < 16; k++) {
            a0 += hv[w][k]      * Wcs[k * 64 + lane];
            a1 += hv[w][16 + k] * Wcs[1024 + k * 64 + lane];
        }
        float acc = bc[lane] + i0 * a0 + i1 * a1;
        float h = fmaxf(acc, 0.f);
        hs[w][lane] = h;
        __syncthreads();
        float hp = hps[w][lane];
        float gr = ldv(b_ih, lane, isf), gz = ldv(b_ih, 64 + lane, isf), gn = ldv(b_ih, 128 + lane, isf);
        float hr = ldv(b_hh, lane, isf), hz = ldv(b_hh, 64 + lane, isf), hn = ldv(b_hh, 128 + lane, isf);
        #pragma unroll 4
        for (int p = 0; p < 32; p++) {
            float a0v = hs[w][2 * p], a1v = hs[w][2 * p + 1];
            float c0 = hps[w][2 * p], c1 = hps[w][2 * p + 1];
            u32 wi0 = Wi[p * 192 + lane], wi1 = Wi[p * 192 + 64 + lane], wi2 = Wi[p * 192 + 128 + lane];
            u32 wh0 = Wh[p * 192 + lane], wh1 = Wh[p * 192 + 64 + lane], wh2 = Wh[p * 192 + 128 + lane];
            gr += a0v * lo16(wi0) + a1v * hi16(wi0);
            gz += a0v * lo16(wi1) + a1v * hi16(wi1);
            gn += a0v * lo16(wi2) + a1v * hi16(wi2);
            hr += c0 * lo16(wh0) + c1 * hi16(wh0);
            hz += c0 * lo16(wh1) + c1 * hi16(wh1);
            hn += c0 * lo16(wh2) + c1 * hi16(wh2);
        }
        float r  = 1.f / (1.f + __expf(-(gr + hr)));
        float z  = 1.f / (1.f + __expf(-(gz + hz)));
        float nv = tanhf(gn + r * hn);
        float hnext = (1.f - z) * nv + z * hp;
        stv(out, (long)n * 64 + lane, hnext, isf);
        float p0 = hnext * ldv(W_out, lane * 64 + 0, isf);
        float p1 = hnext * ldv(W_out, lane * 64 + 1, isf);
        float p2 = hnext * ldv(W_out, lane * 64 + 2, isf);
        #pragma unroll
        for (int off = 32; off; off >>= 1) {
            p0 += __shfl_xor(p0, off);
            p1 += __shfl_xor(p1, off);
            p2 += __shfl_xor(p2, off);
        }
        if (lane == 0) {
            long pb = (long)NN * 64 + (long)n * 3;
            stv(out, pb + 0, p0 + ldv(b_out, 0, isf), isf);
            stv(out, pb + 1, p1 + ldv(b_out, 1, isf), isf);
            stv(out, pb + 2, p2 + ldv(b_out, 2, isf), isf);
        }
    }
}

extern "C" void kernel_launch(void* const* d_in, const int* in_sizes, int n_in,
                              void* d_out, int out_size, void* d_ws, size_t ws_size,
                              hipStream_t stream) {
    const void* x      = d_in[0];
    const void* h_prev = d_in[1];
    const int* en      = (const int*)d_in[2];
    const int* eh      = (const int*)d_in[3];
    const int* ea      = (const int*)d_in[4];
    const void* W_conv = d_in[5];
    const void* b_conv = d_in[6];
    const void* W_mix  = d_in[7];
    const void* b_mix  = d_in[8];
    const void* W_ih   = d_in[9];
    const void* W_hh   = d_in[10];
    const void* b_ih   = d_in[11];
    const void* b_hh   = d_in[12];
    const void* W_out  = d_in[13];
    const void* b_out  = d_in[14];
    void* out          = d_out;

    float* ws     = (float*)d_ws;
    float* ex16   = ws + OFF_EX;
    float* agg16  = ws + OFF_AGG;
    float* Bdeg   = ws + OFF_BDEG;
    float* Ddeg   = ws + OFF_DDEG;
    float* Wc     = ws + OFF_WC;
    float* bcomb  = ws + OFF_BCOMB;
    u32* Wih_pk   = (u32*)(ws + OFF_WIH);
    u32* Whh_pk   = (u32*)(ws + OFF_WHH);
    u32* flag     = (u32*)(ws + OFF_FLAG);

    (void)hipMemsetAsync(d_ws, 0, ZERO_BYTES, stream);
    detect_kernel<<<1, 256, 0, stream>>>((const u32*)x, flag);
    setup_kernel<<<1, 256, 0, stream>>>(W_conv, b_conv, W_mix, b_mix, W_ih, W_hh,
                                        Wc, bcomb, Wih_pk, Whh_pk, flag);
    deg_kernel<<<(EE + 255) / 256, 256, 0, stream>>>(en, eh, ea, Bdeg, Ddeg);
    scat1<<<8192, 256, 0, stream>>>(en, eh, ea, x, ex16, flag);
    scat2<<<8192, 256, 0, stream>>>(en, eh, ea, ex16, Bdeg, agg16);
    epilogue<<<2048, 256, 0, stream>>>(agg16, Ddeg, Wc, bcomb, Wih_pk, Whh_pk,
                                       b_ih, b_hh, h_prev, W_out, b_out, out, flag);
}

// Round 6
// 626.851 us; speedup vs baseline: 1.3707x; 1.3707x over previous
//
#include <hip/hip_runtime.h>

#define NN      100000
#define MHE     200000
#define EE      2000000

typedef unsigned short u16;
typedef unsigned int   u32;
typedef unsigned long long ull;
typedef __attribute__((ext_vector_type(8))) short  s16x8;
typedef __attribute__((ext_vector_type(4))) float  f32x4;
typedef __attribute__((ext_vector_type(4))) unsigned int u32x4;

__device__ __forceinline__ float bf2f(u16 u) { return __uint_as_float(((u32)u) << 16); }
__device__ __forceinline__ u16 f2bf(float f) {
    u32 u = __float_as_uint(f);
    return (u16)((u + 0x7fffu + ((u >> 16) & 1u)) >> 16);
}

// dtype-aware scalar load/store (isf32: 1 = float32 buffers, 0 = bf16 buffers)
__device__ __forceinline__ float ldv(const void* p, long i, int isf32) {
    return isf32 ? ((const float*)p)[i] : bf2f(((const u16*)p)[i]);
}
__device__ __forceinline__ u16 ldb(const void* p, long i, int isf32) {
    return isf32 ? f2bf(((const float*)p)[i]) : ((const u16*)p)[i];
}
__device__ __forceinline__ void stv(void* p, long i, float v, int isf32) {
    if (isf32) ((float*)p)[i] = v;
    else       ((u16*)p)[i] = f2bf(v);
}

union FragU { s16x8 v; ull q[2]; u16 u[8]; };

// load 8 consecutive elements as a bf16x8 fragment (from f32 or bf16 buffer)
__device__ __forceinline__ s16x8 ld8bf(const void* p, long off, int isf32) {
    FragU f;
    if (isf32) {
        const float* fp = (const float*)p + off;
        f32x4 a = *(const f32x4*)fp;
        f32x4 b = *(const f32x4*)(fp + 4);
        f.u[0]=f2bf(a[0]); f.u[1]=f2bf(a[1]); f.u[2]=f2bf(a[2]); f.u[3]=f2bf(a[3]);
        f.u[4]=f2bf(b[0]); f.u[5]=f2bf(b[1]); f.u[6]=f2bf(b[2]); f.u[7]=f2bf(b[3]);
    } else {
        u32x4 w = *(const u32x4*)((const u16*)p + off);
        f.q[0] = ((ull)w[1] << 32) | w[0];
        f.q[1] = ((ull)w[3] << 32) | w[2];
    }
    return f.v;
}

__device__ __forceinline__ float sigm(float x) { return 1.f / (1.f + __expf(-x)); }

// ---- ws layout (f32 units) ----
#define OFF_EX    0           // ex16  [2][MHE][16]
#define OFF_AGG   6400000     // agg16 [2][NN][16]
#define OFF_BDEG  9600000     // [2][MHE]
#define OFF_DDEG  10000000    // [2][NN]
#define OFF_BCOMB 10200000    // [64] f32
#define OFF_WIHB  10200064    // u16[192*64] bf16 row-major
#define OFF_WHHB  10206208    // u16[192*64]
#define OFF_WCB   10212352    // u16[64*32]  combined conv+mix, [col j][k]
#define OFF_FLAG  10213376    // u32
#define ZERO_BYTES (10200000UL * 4UL)

// Detect input dtype (bf16 N(0,1) data never decodes low-u16 to |v|>1e10; f32 mantissas do ~37%)
__global__ void detect_kernel(const u32* __restrict__ xw, u32* __restrict__ flag) {
    __shared__ int cnt;
    if (threadIdx.x == 0) cnt = 0;
    __syncthreads();
    int hits = 0;
    for (int i = threadIdx.x; i < 1024; i += 256) {
        float v = bf2f((u16)(xw[i] & 0xffffu));
        if (!(fabsf(v) < 1e10f)) hits++;
    }
    atomicAdd(&cnt, hits);
    __syncthreads();
    if (threadIdx.x == 0) flag[0] = (cnt >= 16) ? 1u : 0u;
}

// Parallel setup: bf16 copies of W_ih/W_hh, combined Wcb, bcomb.
__global__ __launch_bounds__(256) void setup_kernel(
        const void* __restrict__ W_conv, const void* __restrict__ b_conv,
        const void* __restrict__ W_mix,  const void* __restrict__ b_mix,
        const void* __restrict__ W_ih,   const void* __restrict__ W_hh,
        float* __restrict__ bcomb, u16* __restrict__ Wihb, u16* __restrict__ Whhb,
        u16* __restrict__ Wcb, const u32* __restrict__ flag) {
    int isf = (int)flag[0];
    int gid = blockIdx.x * 256 + threadIdx.x;
    if (gid < 12288) {
        Wihb[gid] = ldb(W_ih, gid, isf);
    } else if (gid < 24576) {
        int i = gid - 12288;
        Whhb[i] = ldb(W_hh, i, isf);
    } else if (gid < 26624) {                 // Wcb[j][k] = sum_c W_conv[t0][kk][c]*W_mix[t0*64+c][j]
        int i = gid - 24576;                  // i = j*32 + k
        int j = i >> 5, k = i & 31;
        int t0 = k >> 4, kk = k & 15;
        float acc = 0.f;
        for (int c = 0; c < 64; c++)
            acc += ldv(W_conv, (t0 * 16 + kk) * 64 + c, isf) * ldv(W_mix, (t0 * 64 + c) * 64 + j, isf);
        Wcb[i] = f2bf(acc);
    } else if (gid < 26688) {                 // bcomb
        int j = gid - 26624;
        float acc = ldv(b_mix, j, isf);
        for (int c = 0; c < 128; c++)
            acc += ldv(b_conv, c, isf) * ldv(W_mix, c * 64 + j, isf);
        bcomb[j] = acc;
    }
}

// node -> hyperedge scatter (+ degree counts fused). 16 lanes per edge.
__global__ __launch_bounds__(256) void scat1(const int* __restrict__ en, const int* __restrict__ eh,
                                             const int* __restrict__ ea,
                                             const void* __restrict__ x,
                                             float* __restrict__ ex16,
                                             float* __restrict__ Bdeg, float* __restrict__ Ddeg,
                                             const u32* __restrict__ flag) {
    int isf = (int)flag[0];
    int sub = threadIdx.x & 15;
    int gid = (blockIdx.x * 256 + threadIdx.x) >> 4;
    int ng  = (gridDim.x * 256) >> 4;
    for (int e = gid; e < EE; e += ng) {
        int t = ea[e], node = en[e], he = eh[e];
        float v = ldv(x, (long)node * 16 + sub, isf);
        atomicAdd(ex16 + ((long)t * MHE + he) * 16 + sub, v);
        if (sub == 0) atomicAdd(Bdeg + (long)t * MHE + he, 1.0f);
        else if (sub == 1) atomicAdd(Ddeg + (long)t * NN + node, 1.0f);
    }
}

// hyperedge -> node scatter with fused Binv. 16 lanes per edge.
__global__ __launch_bounds__(256) void scat2(const int* __restrict__ en, const int* __restrict__ eh,
                                             const int* __restrict__ ea,
                                             const float* __restrict__ ex16,
                                             const float* __restrict__ Bdeg,
                                             float* __restrict__ agg16) {
    int sub = threadIdx.x & 15;
    int gid = (blockIdx.x * 256 + threadIdx.x) >> 4;
    int ng  = (gridDim.x * 256) >> 4;
    for (int e = gid; e < EE; e += ng) {
        int t = ea[e], node = en[e], he = eh[e];
        float bd = Bdeg[(long)t * MHE + he];
        float v  = ex16[((long)t * MHE + he) * 16 + sub] * (1.0f / fmaxf(bd, 1.0f));
        atomicAdd(agg16 + ((long)t * NN + node) * 16 + sub, v);
    }
}

// MFMA epilogue (see R5 notes). LDS C->A roundtrip now uses type-consistent u16
// reads + a compiler memory fence (the ull-pun was a TBAA violation -> reordering).
__global__ __launch_bounds__(256) void epilogue(const float* __restrict__ agg16,
                                                const float* __restrict__ Ddeg,
                                                const float* __restrict__ bcomb,
                                                const u16* __restrict__ Wihb,
                                                const u16* __restrict__ Whhb,
                                                const u16* __restrict__ Wcb,
                                                const void* __restrict__ b_ih, const void* __restrict__ b_hh,
                                                const void* __restrict__ h_prev,
                                                const void* __restrict__ W_out, const void* __restrict__ b_out,
                                                void* __restrict__ out,
                                                const u32* __restrict__ flag) {
    __shared__ u16 hA[4][16][72];   // per-wave h tile, row-padded, bf16
    int isf = (int)flag[0];
    int tid = threadIdx.x;
    int w = tid >> 6, lane = tid & 63;
    int cl = lane & 15, q = lane >> 4;
    u16* hAw = &hA[w][0][0];

    float bcj[4], br[4], bz[4], bin_[4], bhn[4], wo0[4], wo1[4], wo2[4];
    #pragma unroll
    for (int c = 0; c < 4; c++) {
        int j = c * 16 + cl;
        bcj[c]  = bcomb[j];
        br[c]   = ldv(b_ih, j, isf)       + ldv(b_hh, j, isf);
        bz[c]   = ldv(b_ih, 64 + j, isf)  + ldv(b_hh, 64 + j, isf);
        bin_[c] = ldv(b_ih, 128 + j, isf);
        bhn[c]  = ldv(b_hh, 128 + j, isf);
        wo0[c]  = ldv(W_out, (long)j * 64 + 0, isf);
        wo1[c]  = ldv(W_out, (long)j * 64 + 1, isf);
        wo2[c]  = ldv(W_out, (long)j * 64 + 2, isf);
    }
    float bo0 = ldv(b_out, 0, isf), bo1 = ldv(b_out, 1, isf), bo2 = ldv(b_out, 2, isf);

    for (int wt = blockIdx.x * 4 + w; wt < NN / 16; wt += gridDim.x * 4) {
        long nb = (long)wt * 16;
        // ---- stage 1: h = relu(bcomb + (Dinv*agg16) @ Wcb) ----
        {
            int m = cl;
            int t0 = q >> 1;
            long nidx = nb + m;
            const float* ap = agg16 + ((long)t0 * NN + nidx) * 16 + (q & 1) * 8;
            f32x4 a0 = *(const f32x4*)ap;
            f32x4 a1 = *(const f32x4*)(ap + 4);
            float dd = Ddeg[(long)t0 * NN + nidx];
            float isc = dd > 0.f ? 1.0f / dd : 0.f;
            FragU fa;
            fa.u[0]=f2bf(a0[0]*isc); fa.u[1]=f2bf(a0[1]*isc); fa.u[2]=f2bf(a0[2]*isc); fa.u[3]=f2bf(a0[3]*isc);
            fa.u[4]=f2bf(a1[0]*isc); fa.u[5]=f2bf(a1[1]*isc); fa.u[6]=f2bf(a1[2]*isc); fa.u[7]=f2bf(a1[3]*isc);
            f32x4 hacc[4];
            #pragma unroll
            for (int c = 0; c < 4; c++) {
                hacc[c] = (f32x4){0.f, 0.f, 0.f, 0.f};
                s16x8 bfr = *(const s16x8*)(Wcb + (c * 16 + cl) * 32 + q * 8);
                hacc[c] = __builtin_amdgcn_mfma_f32_16x16x32_bf16(fa.v, bfr, hacc[c], 0, 0, 0);
            }
            #pragma unroll
            for (int c = 0; c < 4; c++) {
                #pragma unroll
                for (int reg = 0; reg < 4; reg++) {
                    int row = q * 4 + reg;
                    float hv = fmaxf(hacc[c][reg] + bcj[c], 0.f);
                    hAw[row * 72 + c * 16 + cl] = f2bf(hv);
                }
            }
        }
        // compiler memory fence: no reordering of the u16 LDS reads below
        // above the u16 LDS writes (HW LDS pipe is in-order per wave).
        asm volatile("" ::: "memory");
        // ---- stage 2: GRU matmuls ----
        int m = cl;
        const u16* hrow = hAw + m * 72;
        FragU ha0, ha1;
        #pragma unroll
        for (int j = 0; j < 8; j++) {
            ha0.u[j] = hrow[q * 8 + j];
            ha1.u[j] = hrow[32 + q * 8 + j];
        }
        s16x8 hp0 = ld8bf(h_prev, (nb + m) * 64 + q * 8, isf);
        s16x8 hp1 = ld8bf(h_prev, (nb + m) * 64 + 32 + q * 8, isf);

        f32x4 accr[4], accz[4], accin[4], acchn[4];
        #pragma unroll
        for (int c = 0; c < 4; c++) {
            accr[c]  = (f32x4){br[c], br[c], br[c], br[c]};
            accz[c]  = (f32x4){bz[c], bz[c], bz[c], bz[c]};
            accin[c] = (f32x4){bin_[c], bin_[c], bin_[c], bin_[c]};
            acchn[c] = (f32x4){bhn[c], bhn[c], bhn[c], bhn[c]};
        }
        #pragma unroll
        for (int s = 0; s < 2; s++) {
            s16x8 hf  = s ? ha1.v : ha0.v;
            s16x8 hpf = s ? hp1 : hp0;
            int ko = s * 32 + q * 8;
            #pragma unroll
            for (int c = 0; c < 4; c++) {
                int rr = c * 16 + cl;
                s16x8 bir  = *(const s16x8*)(Wihb + (long)rr * 64 + ko);
                s16x8 bhr  = *(const s16x8*)(Whhb + (long)rr * 64 + ko);
                s16x8 biz  = *(const s16x8*)(Wihb + (long)(64 + rr) * 64 + ko);
                s16x8 bhz  = *(const s16x8*)(Whhb + (long)(64 + rr) * 64 + ko);
                s16x8 bin2 = *(const s16x8*)(Wihb + (long)(128 + rr) * 64 + ko);
                s16x8 bhn2 = *(const s16x8*)(Whhb + (long)(128 + rr) * 64 + ko);
                accr[c]  = __builtin_amdgcn_mfma_f32_16x16x32_bf16(hf,  bir, accr[c], 0, 0, 0);
                accr[c]  = __builtin_amdgcn_mfma_f32_16x16x32_bf16(hpf, bhr, accr[c], 0, 0, 0);
                accz[c]  = __builtin_amdgcn_mfma_f32_16x16x32_bf16(hf,  biz, accz[c], 0, 0, 0);
                accz[c]  = __builtin_amdgcn_mfma_f32_16x16x32_bf16(hpf, bhz, accz[c], 0, 0, 0);
                accin[c] = __builtin_amdgcn_mfma_f32_16x16x32_bf16(hf,  bin2, accin[c], 0, 0, 0);
                acchn[c] = __builtin_amdgcn_mfma_f32_16x16x32_bf16(hpf, bhn2, acchn[c], 0, 0, 0);
            }
        }
        // ---- gates + h_next + pred (C-layout: row=q*4+reg, col=c*16+cl) ----
        float p0[4] = {0,0,0,0}, p1[4] = {0,0,0,0}, p2[4] = {0,0,0,0};
        #pragma unroll
        for (int c = 0; c < 4; c++) {
            #pragma unroll
            for (int reg = 0; reg < 4; reg++) {
                float rr = sigm(accr[c][reg]);
                float zz = sigm(accz[c][reg]);
                float ng = tanhf(accin[c][reg] + rr * acchn[c][reg]);
                long n = nb + q * 4 + reg;
                long j = c * 16 + cl;
                float hp = ldv(h_prev, n * 64 + j, isf);
                float hx = (1.f - zz) * ng + zz * hp;
                stv(out, n * 64 + j, hx, isf);
                p0[reg] += hx * wo0[c];
                p1[reg] += hx * wo1[c];
                p2[reg] += hx * wo2[c];
            }
        }
        #pragma unroll
        for (int reg = 0; reg < 4; reg++) {
            #pragma unroll
            for (int off = 1; off < 16; off <<= 1) {
                p0[reg] += __shfl_xor(p0[reg], off);
                p1[reg] += __shfl_xor(p1[reg], off);
                p2[reg] += __shfl_xor(p2[reg], off);
            }
        }
        if (cl == 0) {
            #pragma unroll
            for (int reg = 0; reg < 4; reg++) {
                long n = nb + q * 4 + reg;
                long pb = (long)NN * 64 + n * 3;
                stv(out, pb + 0, p0[reg] + bo0, isf);
                stv(out, pb + 1, p1[reg] + bo1, isf);
                stv(out, pb + 2, p2[reg] + bo2, isf);
            }
        }
    }
}

extern "C" void kernel_launch(void* const* d_in, const int* in_sizes, int n_in,
                              void* d_out, int out_size, void* d_ws, size_t ws_size,
                              hipStream_t stream) {
    const void* x      = d_in[0];
    const void* h_prev = d_in[1];
    const int* en      = (const int*)d_in[2];
    const int* eh      = (const int*)d_in[3];
    const int* ea      = (const int*)d_in[4];
    const void* W_conv = d_in[5];
    const void* b_conv = d_in[6];
    const void* W_mix  = d_in[7];
    const void* b_mix  = d_in[8];
    const void* W_ih   = d_in[9];
    const void* W_hh   = d_in[10];
    const void* b_ih   = d_in[11];
    const void* b_hh   = d_in[12];
    const void* W_out  = d_in[13];
    const void* b_out  = d_in[14];
    void* out          = d_out;

    float* ws    = (float*)d_ws;
    float* ex16  = ws + OFF_EX;
    float* agg16 = ws + OFF_AGG;
    float* Bdeg  = ws + OFF_BDEG;
    float* Ddeg  = ws + OFF_DDEG;
    float* bcomb = ws + OFF_BCOMB;
    u16* Wihb    = (u16*)(ws + OFF_WIHB);
    u16* Whhb    = (u16*)(ws + OFF_WHHB);
    u16* Wcb     = (u16*)(ws + OFF_WCB);
    u32* flag    = (u32*)(ws + OFF_FLAG);

    (void)hipMemsetAsync(d_ws, 0, ZERO_BYTES, stream);
    detect_kernel<<<1, 256, 0, stream>>>((const u32*)x, flag);
    setup_kernel<<<105, 256, 0, stream>>>(W_conv, b_conv, W_mix, b_mix, W_ih, W_hh,
                                          bcomb, Wihb, Whhb, Wcb, flag);
    scat1<<<8192, 256, 0, stream>>>(en, eh, ea, x, ex16, Bdeg, Ddeg, flag);
    scat2<<<8192, 256, 0, stream>>>(en, eh, ea, ex16, Bdeg, agg16);
    epilogue<<<1563, 256, 0, stream>>>(agg16, Ddeg, bcomb, Wihb, Whhb, Wcb,
                                       b_ih, b_hh, h_prev, W_out, b_out, out, flag);
}

// Round 7
// 614.589 us; speedup vs baseline: 1.3981x; 1.0200x over previous
//
#include <hip/hip_runtime.h>

#define NN      100000
#define MHE     200000
#define EE      2000000
#define H1      400000      // hedge keys (2 types)
#define H2      200000      // node keys (2 types)
#define NK      600000      // total keys
#define NB      293         // scan blocks of 2048

typedef unsigned short u16;
typedef unsigned int   u32;
typedef unsigned long long ull;
typedef __attribute__((ext_vector_type(8))) short  s16x8;
typedef __attribute__((ext_vector_type(4))) float  f32x4;
typedef __attribute__((ext_vector_type(4))) unsigned int u32x4;

__device__ __forceinline__ float bf2f(u16 u) { return __uint_as_float(((u32)u) << 16); }
__device__ __forceinline__ u16 f2bf(float f) {
    u32 u = __float_as_uint(f);
    return (u16)((u + 0x7fffu + ((u >> 16) & 1u)) >> 16);
}
__device__ __forceinline__ float ldv(const void* p, long i, int isf32) {
    return isf32 ? ((const float*)p)[i] : bf2f(((const u16*)p)[i]);
}
__device__ __forceinline__ u16 ldb(const void* p, long i, int isf32) {
    return isf32 ? f2bf(((const float*)p)[i]) : ((const u16*)p)[i];
}
__device__ __forceinline__ void stv(void* p, long i, float v, int isf32) {
    if (isf32) ((float*)p)[i] = v;
    else       ((u16*)p)[i] = f2bf(v);
}

union FragU { s16x8 v; ull q[2]; u16 u[8]; };

__device__ __forceinline__ s16x8 ld8bf(const void* p, long off, int isf32) {
    FragU f;
    if (isf32) {
        const float* fp = (const float*)p + off;
        f32x4 a = *(const f32x4*)fp;
        f32x4 b = *(const f32x4*)(fp + 4);
        f.u[0]=f2bf(a[0]); f.u[1]=f2bf(a[1]); f.u[2]=f2bf(a[2]); f.u[3]=f2bf(a[3]);
        f.u[4]=f2bf(b[0]); f.u[5]=f2bf(b[1]); f.u[6]=f2bf(b[2]); f.u[7]=f2bf(b[3]);
    } else {
        u32x4 w = *(const u32x4*)((const u16*)p + off);
        f.q[0] = ((ull)w[1] << 32) | w[0];
        f.q[1] = ((ull)w[3] << 32) | w[2];
    }
    return f.v;
}

__device__ __forceinline__ float sigm(float x) { return 1.f / (1.f + __expf(-x)); }

// ---- ws layout (f32 units) ----
// slot1/slot2 (ints, 2M each) alias the ex16 region (dead before gatherA writes it).
#define OFF_EX     0            // ex16 f32[6,400,000]; slot1=int[2M]@0, slot2=int[2M]@2,000,000
#define OFF_AGG    6400000      // agg16 f32[3,200,000]
#define OFF_OFFA   9600000      // off  int[600,001]
#define OFF_HIST   10200064     // hist int[600,000]
#define OFF_PART   10800064     // partials int[512]
#define OFF_CSR    10800576     // csr  int[4,000,000]
#define OFF_BCOMB  14800576     // f32[64]
#define OFF_WIHB   14800640     // u16[12288]
#define OFF_WHHB   14806784     // u16[12288]
#define OFF_WCB    14812928     // u16[1024]
#define OFF_FLAG   14813440     // u32

__global__ void detect_kernel(const u32* __restrict__ xw, u32* __restrict__ flag) {
    __shared__ int cnt;
    if (threadIdx.x == 0) cnt = 0;
    __syncthreads();
    int hits = 0;
    for (int i = threadIdx.x; i < 1024; i += 256) {
        float v = bf2f((u16)(xw[i] & 0xffffu));
        if (!(fabsf(v) < 1e10f)) hits++;
    }
    atomicAdd(&cnt, hits);
    __syncthreads();
    if (threadIdx.x == 0) flag[0] = (cnt >= 16) ? 1u : 0u;
}

__global__ __launch_bounds__(256) void setup_kernel(
        const void* __restrict__ W_conv, const void* __restrict__ b_conv,
        const void* __restrict__ W_mix,  const void* __restrict__ b_mix,
        const void* __restrict__ W_ih,   const void* __restrict__ W_hh,
        float* __restrict__ bcomb, u16* __restrict__ Wihb, u16* __restrict__ Whhb,
        u16* __restrict__ Wcb, const u32* __restrict__ flag) {
    int isf = (int)flag[0];
    int gid = blockIdx.x * 256 + threadIdx.x;
    if (gid < 12288) {
        Wihb[gid] = ldb(W_ih, gid, isf);
    } else if (gid < 24576) {
        int i = gid - 12288;
        Whhb[i] = ldb(W_hh, i, isf);
    } else if (gid < 26624) {                 // Wcb[j][k]: k = t0*16+kk
        int i = gid - 24576;
        int j = i >> 5, k = i & 31;
        int t0 = k >> 4, kk = k & 15;
        float acc = 0.f;
        for (int c = 0; c < 64; c++)
            acc += ldv(W_conv, (t0 * 16 + kk) * 64 + c, isf) * ldv(W_mix, (t0 * 64 + c) * 64 + j, isf);
        Wcb[i] = f2bf(acc);
    } else if (gid < 26688) {
        int j = gid - 26624;
        float acc = ldv(b_mix, j, isf);
        for (int c = 0; c < 128; c++)
            acc += ldv(b_conv, c, isf) * ldv(W_mix, c * 64 + j, isf);
        bcomb[j] = acc;
    }
}

// histogram both keys; record per-edge rank (slot) for atomic-free fill
__global__ __launch_bounds__(256) void hist_kernel(const int* __restrict__ en, const int* __restrict__ eh,
                                                   const int* __restrict__ ea,
                                                   int* __restrict__ hist,
                                                   int* __restrict__ slot1, int* __restrict__ slot2) {
    int i = blockIdx.x * 256 + threadIdx.x;
    if (i >= EE) return;
    int t = ea[i];
    int k1 = t * MHE + eh[i];
    int k2 = H1 + t * NN + en[i];
    slot1[i] = atomicAdd(hist + k1, 1);
    slot2[i] = atomicAdd(hist + k2, 1);
}

// scan stage A: per-2048-block sums
__global__ __launch_bounds__(256) void scanA(const int* __restrict__ hist, int* __restrict__ partials) {
    __shared__ int lds[256];
    int b = blockIdx.x, t = threadIdx.x;
    int base = b * 2048 + t * 8;
    int s = 0;
    #pragma unroll
    for (int j = 0; j < 8; j++) {
        int idx = base + j;
        if (idx < NK) s += hist[idx];
    }
    lds[t] = s;
    __syncthreads();
    for (int d = 128; d > 0; d >>= 1) {
        if (t < d) lds[t] += lds[t + d];
        __syncthreads();
    }
    if (t == 0) partials[b] = lds[0];
}

// scan stage B: serial exclusive scan of NB partials; writes off[NK]=total
__global__ void scanB(int* __restrict__ partials, int* __restrict__ off) {
    if (threadIdx.x == 0 && blockIdx.x == 0) {
        int run = 0;
        for (int b = 0; b < NB; b++) {
            int v = partials[b];
            partials[b] = run;
            run += v;
        }
        off[NK] = run;
    }
}

// scan stage C: block-local exclusive scan + base
__global__ __launch_bounds__(256) void scanC(const int* __restrict__ hist, const int* __restrict__ partials,
                                             int* __restrict__ off) {
    __shared__ int lds[256];
    int b = blockIdx.x, t = threadIdx.x;
    int base = b * 2048 + t * 8;
    int v[8];
    int s = 0;
    #pragma unroll
    for (int j = 0; j < 8; j++) {
        int idx = base + j;
        v[j] = (idx < NK) ? hist[idx] : 0;
        s += v[j];
    }
    lds[t] = s;
    __syncthreads();
    // Hillis-Steele inclusive scan
    for (int d = 1; d < 256; d <<= 1) {
        int tmp = (t >= d) ? lds[t - d] : 0;
        __syncthreads();
        lds[t] += tmp;
        __syncthreads();
    }
    int run = partials[b] + lds[t] - s;   // exclusive prefix for this thread's chunk
    #pragma unroll
    for (int j = 0; j < 8; j++) {
        int idx = base + j;
        if (idx < NK) off[idx] = run;
        run += v[j];
    }
}

// atomic-free CSR fill using recorded slots
__global__ __launch_bounds__(256) void fill_kernel(const int* __restrict__ en, const int* __restrict__ eh,
                                                   const int* __restrict__ ea,
                                                   const int* __restrict__ off,
                                                   const int* __restrict__ slot1, const int* __restrict__ slot2,
                                                   int* __restrict__ csr) {
    int i = blockIdx.x * 256 + threadIdx.x;
    if (i >= EE) return;
    int t = ea[i];
    int he = eh[i], n = en[i];
    int k1 = t * MHE + he;
    int k2 = H1 + t * NN + n;
    csr[off[k1] + slot1[i]] = n;
    csr[off[k2] + slot2[i]] = k1;    // hedge linear index
}

// gather-reduce node -> hyperedge, fold Binv. 16 lanes per hyperedge key.
__global__ __launch_bounds__(256) void gatherA(const int* __restrict__ off, const int* __restrict__ csr,
                                               const void* __restrict__ x, float* __restrict__ ex16,
                                               const u32* __restrict__ flag) {
    int isf = (int)flag[0];
    int sub = threadIdx.x & 15;
    int g0  = (blockIdx.x * 256 + threadIdx.x) >> 4;
    int ng  = (gridDim.x * 256) >> 4;
    for (int k = g0; k < H1; k += ng) {
        int beg = off[k], end = off[k + 1];
        float acc = 0.f;
        for (int i = beg; i < end; i++) {
            int nid = csr[i];
            acc += ldv(x, (long)nid * 16 + sub, isf);
        }
        int d = end - beg;
        ex16[(long)k * 16 + sub] = d > 0 ? acc * (1.0f / (float)d) : 0.f;
    }
}

// gather-reduce hyperedge -> node, fold Dinv. 16 lanes per node key.
__global__ __launch_bounds__(256) void gatherB(const int* __restrict__ off, const int* __restrict__ csr,
                                               const float* __restrict__ ex16, float* __restrict__ agg16) {
    int sub = threadIdx.x & 15;
    int g0  = (blockIdx.x * 256 + threadIdx.x) >> 4;
    int ng  = (gridDim.x * 256) >> 4;
    for (int k = g0; k < H2; k += ng) {
        int beg = off[H1 + k], end = off[H1 + k + 1];
        float acc = 0.f;
        for (int i = beg; i < end; i++) {
            int hidx = csr[i];
            acc += ex16[(long)hidx * 16 + sub];
        }
        int d = end - beg;
        agg16[(long)k * 16 + sub] = d > 0 ? acc * (1.0f / (float)d) : 0.f;
    }
}

// MFMA epilogue; agg16 is pre-scaled by Binv and Dinv.
__global__ __launch_bounds__(256) void epilogue(const float* __restrict__ agg16,
                                                const float* __restrict__ bcomb,
                                                const u16* __restrict__ Wihb,
                                                const u16* __restrict__ Whhb,
                                                const u16* __restrict__ Wcb,
                                                const void* __restrict__ b_ih, const void* __restrict__ b_hh,
                                                const void* __restrict__ h_prev,
                                                const void* __restrict__ W_out, const void* __restrict__ b_out,
                                                void* __restrict__ out,
                                                const u32* __restrict__ flag) {
    __shared__ u16 hA[4][16][72];
    int isf = (int)flag[0];
    int tid = threadIdx.x;
    int w = tid >> 6, lane = tid & 63;
    int cl = lane & 15, q = lane >> 4;
    u16* hAw = &hA[w][0][0];

    float bcj[4], br[4], bz[4], bin_[4], bhn[4], wo0[4], wo1[4], wo2[4];
    #pragma unroll
    for (int c = 0; c < 4; c++) {
        int j = c * 16 + cl;
        bcj[c]  = bcomb[j];
        br[c]   = ldv(b_ih, j, isf)       + ldv(b_hh, j, isf);
        bz[c]   = ldv(b_ih, 64 + j, isf)  + ldv(b_hh, 64 + j, isf);
        bin_[c] = ldv(b_ih, 128 + j, isf);
        bhn[c]  = ldv(b_hh, 128 + j, isf);
        wo0[c]  = ldv(W_out, (long)j * 64 + 0, isf);
        wo1[c]  = ldv(W_out, (long)j * 64 + 1, isf);
        wo2[c]  = ldv(W_out, (long)j * 64 + 2, isf);
    }
    float bo0 = ldv(b_out, 0, isf), bo1 = ldv(b_out, 1, isf), bo2 = ldv(b_out, 2, isf);

    for (int wt = blockIdx.x * 4 + w; wt < NN / 16; wt += gridDim.x * 4) {
        long nb = (long)wt * 16;
        {
            int m = cl;
            int t0 = q >> 1;
            long nidx = nb + m;
            const float* ap = agg16 + ((long)t0 * NN + nidx) * 16 + (q & 1) * 8;
            f32x4 a0 = *(const f32x4*)ap;
            f32x4 a1 = *(const f32x4*)(ap + 4);
            FragU fa;
            fa.u[0]=f2bf(a0[0]); fa.u[1]=f2bf(a0[1]); fa.u[2]=f2bf(a0[2]); fa.u[3]=f2bf(a0[3]);
            fa.u[4]=f2bf(a1[0]); fa.u[5]=f2bf(a1[1]); fa.u[6]=f2bf(a1[2]); fa.u[7]=f2bf(a1[3]);
            f32x4 hacc[4];
            #pragma unroll
            for (int c = 0; c < 4; c++) {
                hacc[c] = (f32x4){0.f, 0.f, 0.f, 0.f};
                s16x8 bfr = *(const s16x8*)(Wcb + (c * 16 + cl) * 32 + q * 8);
                hacc[c] = __builtin_amdgcn_mfma_f32_16x16x32_bf16(fa.v, bfr, hacc[c], 0, 0, 0);
            }
            #pragma unroll
            for (int c = 0; c < 4; c++) {
                #pragma unroll
                for (int reg = 0; reg < 4; reg++) {
                    int row = q * 4 + reg;
                    float hv = fmaxf(hacc[c][reg] + bcj[c], 0.f);
                    hAw[row * 72 + c * 16 + cl] = f2bf(hv);
                }
            }
        }
        asm volatile("" ::: "memory");
        int m = cl;
        const u16* hrow = hAw + m * 72;
        FragU ha0, ha1;
        #pragma unroll
        for (int j = 0; j < 8; j++) {
            ha0.u[j] = hrow[q * 8 + j];
            ha1.u[j] = hrow[32 + q * 8 + j];
        }
        s16x8 hp0 = ld8bf(h_prev, (nb + m) * 64 + q * 8, isf);
        s16x8 hp1 = ld8bf(h_prev, (nb + m) * 64 + 32 + q * 8, isf);

        f32x4 accr[4], accz[4], accin[4], acchn[4];
        #pragma unroll
        for (int c = 0; c < 4; c++) {
            accr[c]  = (f32x4){br[c], br[c], br[c], br[c]};
            accz[c]  = (f32x4){bz[c], bz[c], bz[c], bz[c]};
            accin[c] = (f32x4){bin_[c], bin_[c], bin_[c], bin_[c]};
            acchn[c] = (f32x4){bhn[c], bhn[c], bhn[c], bhn[c]};
        }
        #pragma unroll
        for (int s = 0; s < 2; s++) {
            s16x8 hf  = s ? ha1.v : ha0.v;
            s16x8 hpf = s ? hp1 : hp0;
            int ko = s * 32 + q * 8;
            #pragma unroll
            for (int c = 0; c < 4; c++) {
                int rr = c * 16 + cl;
                s16x8 bir  = *(const s16x8*)(Wihb + (long)rr * 64 + ko);
                s16x8 bhr  = *(const s16x8*)(Whhb + (long)rr * 64 + ko);
                s16x8 biz  = *(const s16x8*)(Wihb + (long)(64 + rr) * 64 + ko);
                s16x8 bhz  = *(const s16x8*)(Whhb + (long)(64 + rr) * 64 + ko);
                s16x8 bin2 = *(const s16x8*)(Wihb + (long)(128 + rr) * 64 + ko);
                s16x8 bhn2 = *(const s16x8*)(Whhb + (long)(128 + rr) * 64 + ko);
                accr[c]  = __builtin_amdgcn_mfma_f32_16x16x32_bf16(hf,  bir, accr[c], 0, 0, 0);
                accr[c]  = __builtin_amdgcn_mfma_f32_16x16x32_bf16(hpf, bhr, accr[c], 0, 0, 0);
                accz[c]  = __builtin_amdgcn_mfma_f32_16x16x32_bf16(hf,  biz, accz[c], 0, 0, 0);
                accz[c]  = __builtin_amdgcn_mfma_f32_16x16x32_bf16(hpf, bhz, accz[c], 0, 0, 0);
                accin[c] = __builtin_amdgcn_mfma_f32_16x16x32_bf16(hf,  bin2, accin[c], 0, 0, 0);
                acchn[c] = __builtin_amdgcn_mfma_f32_16x16x32_bf16(hpf, bhn2, acchn[c], 0, 0, 0);
            }
        }
        float p0[4] = {0,0,0,0}, p1[4] = {0,0,0,0}, p2[4] = {0,0,0,0};
        #pragma unroll
        for (int c = 0; c < 4; c++) {
            #pragma unroll
            for (int reg = 0; reg < 4; reg++) {
                float rr = sigm(accr[c][reg]);
                float zz = sigm(accz[c][reg]);
                float ng = tanhf(accin[c][reg] + rr * acchn[c][reg]);
                long n = nb + q * 4 + reg;
                long j = c * 16 + cl;
                float hp = ldv(h_prev, n * 64 + j, isf);
                float hx = (1.f - zz) * ng + zz * hp;
                stv(out, n * 64 + j, hx, isf);
                p0[reg] += hx * wo0[c];
                p1[reg] += hx * wo1[c];
                p2[reg] += hx * wo2[c];
            }
        }
        #pragma unroll
        for (int reg = 0; reg < 4; reg++) {
            #pragma unroll
            for (int off2 = 1; off2 < 16; off2 <<= 1) {
                p0[reg] += __shfl_xor(p0[reg], off2);
                p1[reg] += __shfl_xor(p1[reg], off2);
                p2[reg] += __shfl_xor(p2[reg], off2);
            }
        }
        if (cl == 0) {
            #pragma unroll
            for (int reg = 0; reg < 4; reg++) {
                long n = nb + q * 4 + reg;
                long pb = (long)NN * 64 + n * 3;
                stv(out, pb + 0, p0[reg] + bo0, isf);
                stv(out, pb + 1, p1[reg] + bo1, isf);
                stv(out, pb + 2, p2[reg] + bo2, isf);
            }
        }
    }
}

extern "C" void kernel_launch(void* const* d_in, const int* in_sizes, int n_in,
                              void* d_out, int out_size, void* d_ws, size_t ws_size,
                              hipStream_t stream) {
    const void* x      = d_in[0];
    const void* h_prev = d_in[1];
    const int* en      = (const int*)d_in[2];
    const int* eh      = (const int*)d_in[3];
    const int* ea      = (const int*)d_in[4];
    const void* W_conv = d_in[5];
    const void* b_conv = d_in[6];
    const void* W_mix  = d_in[7];
    const void* b_mix  = d_in[8];
    const void* W_ih   = d_in[9];
    const void* W_hh   = d_in[10];
    const void* b_ih   = d_in[11];
    const void* b_hh   = d_in[12];
    const void* W_out  = d_in[13];
    const void* b_out  = d_in[14];
    void* out          = d_out;

    float* ws    = (float*)d_ws;
    float* ex16  = ws + OFF_EX;
    float* agg16 = ws + OFF_AGG;
    int* slot1   = (int*)(ws + OFF_EX);            // aliases ex16 (dead before gatherA)
    int* slot2   = (int*)(ws + OFF_EX) + 2000000;
    int* offa    = (int*)(ws + OFF_OFFA);
    int* hist    = (int*)(ws + OFF_HIST);
    int* part    = (int*)(ws + OFF_PART);
    int* csr     = (int*)(ws + OFF_CSR);
    float* bcomb = ws + OFF_BCOMB;
    u16* Wihb    = (u16*)(ws + OFF_WIHB);
    u16* Whhb    = (u16*)(ws + OFF_WHHB);
    u16* Wcb     = (u16*)(ws + OFF_WCB);
    u32* flag    = (u32*)(ws + OFF_FLAG);

    (void)hipMemsetAsync(hist, 0, (size_t)NK * 4, stream);
    detect_kernel<<<1, 256, 0, stream>>>((const u32*)x, flag);
    setup_kernel<<<105, 256, 0, stream>>>(W_conv, b_conv, W_mix, b_mix, W_ih, W_hh,
                                          bcomb, Wihb, Whhb, Wcb, flag);
    hist_kernel<<<(EE + 255) / 256, 256, 0, stream>>>(en, eh, ea, hist, slot1, slot2);
    scanA<<<NB, 256, 0, stream>>>(hist, part);
    scanB<<<1, 64, 0, stream>>>(part, offa);
    scanC<<<NB, 256, 0, stream>>>(hist, part, offa);
    fill_kernel<<<(EE + 255) / 256, 256, 0, stream>>>(en, eh, ea, offa, slot1, slot2, csr);
    gatherA<<<8192, 256, 0, stream>>>(offa, csr, x, ex16, flag);
    gatherB<<<8192, 256, 0, stream>>>(offa, csr, ex16, agg16);
    epilogue<<<1563, 256, 0, stream>>>(agg16, bcomb, Wihb, Whhb, Wcb,
                                       b_ih, b_hh, h_prev, W_out, b_out, out, flag);
}